// Round 9
// baseline (127.912 us; speedup 1.0000x reference)
//
#include <hip/hip_runtime.h>
#include <math.h>

#define N_Q     16384
#define DDIM    512
#define M_SLOTS 2048
#define EPSN    1e-12f
#define TEMPU   1e-5f
#define KSCALE  25.4f                    // int8 scale for keys (clips at ~5 sigma)
#define QSCALE  127.0f
#define INV_S   (1.0f / (127.0f * 25.4f))

typedef unsigned int u32;
typedef unsigned long long u64;
typedef __attribute__((ext_vector_type(4))) int i32x4;

// ---------- helpers ----------
__device__ __forceinline__ float block_reduce_sum_128(float v, float* sred, int t) {
    #pragma unroll
    for (int o = 32; o > 0; o >>= 1) v += __shfl_down(v, o, 64);
    if ((t & 63) == 0) sred[t >> 6] = v;
    __syncthreads();
    return sred[0] + sred[1];
}
__device__ __forceinline__ char q8(float x, float s) {
    int v = __float2int_rn(x * s);
    v = v < -127 ? -127 : (v > 127 ? 127 : v);
    return (char)v;
}

// ---------- kernel 1: normalize+quantize queries (blocks 0..N_Q-1), keys->i8 (last 2048) ----------
__global__ __launch_bounds__(128) void k_prep(const float* __restrict__ q,
                                              const float* __restrict__ keys,
                                              char* __restrict__ qi8,
                                              char* __restrict__ ki8) {
    __shared__ float sred[2];
    int b = blockIdx.x;
    int t = threadIdx.x;
    if (b < N_Q) {
        float4 v = ((const float4*)(q + (size_t)b * DDIM))[t];
        float ss = v.x * v.x + v.y * v.y + v.z * v.z + v.w * v.w;
        ss = block_reduce_sum_128(ss, sred, t);
        float s = QSCALE / fmaxf(sqrtf(ss), EPSN);
        char4 o;
        o.x = q8(v.x, s);
        o.y = q8(v.y, s);
        o.z = q8(v.z, s);
        o.w = q8(v.w, s);
        ((char4*)(qi8 + (size_t)b * DDIM))[t] = o;
    } else {
        int r = b - N_Q;
        float4 v = ((const float4*)(keys + (size_t)r * DDIM))[t];
        char4 o;
        o.x = q8(v.x, KSCALE);
        o.y = q8(v.y, KSCALE);
        o.z = q8(v.z, KSCALE);
        o.w = q8(v.w, KSCALE);
        ((char4*)(ki8 + (size_t)r * DDIM))[t] = o;
    }
}

// ---------- kernel 2: i8 MFMA score GEMM — pure-register streaming, no LDS ----------
// Wave tile 32x64, 4 waves/block (block 128 rows x 64 cols), grid 32x128.
// A (this wave's 32 rows, full K=512) lives in 64 VGPR, loaded once via 2 base
// ptrs + kt*64 immediate offsets. B frags stream from L2 (keys = 1MB,
// L2-resident) via 4 base ptrs + immediates. No LDS, no barriers; latency
// hidden by occupancy (3 waves/SIMD) + compiler-scheduled unrolled loads.
__global__ __launch_bounds__(256, 3) void k_score(const char* __restrict__ qi8,
                                                  const char* __restrict__ ki8,
                                                  u64* __restrict__ rowpack,
                                                  u32* __restrict__ colmax) {
    int t = threadIdx.x;
    int lane = t & 63;
    int w = t >> 6;              // wave 0..3 -> rows w*32 .. +32
    int lr = lane & 15;          // frag row (A) / col (B)
    int kc = lane >> 4;          // k-chunk 0..3 (16 i8 each)

    int j0 = blockIdx.x * 64;    // slot block (64 cols)
    int n0 = blockIdx.y * 128;   // query block (128 rows)
    int wr0 = n0 + w * 32;       // this wave's first row

    const char* ga0 = qi8 + (size_t)(wr0 + lr) * DDIM + kc * 16;
    const char* ga1 = qi8 + (size_t)(wr0 + 16 + lr) * DDIM + kc * 16;
    const char* gb0 = ki8 + (size_t)(j0 + lr) * DDIM + kc * 16;
    const char* gb1 = ki8 + (size_t)(j0 + 16 + lr) * DDIM + kc * 16;
    const char* gb2 = ki8 + (size_t)(j0 + 32 + lr) * DDIM + kc * 16;
    const char* gb3 = ki8 + (size_t)(j0 + 48 + lr) * DDIM + kc * 16;

    // A upfront: 16 independent loads, all via immediate offsets
    i32x4 a[8][2];
    #pragma unroll
    for (int kt = 0; kt < 8; ++kt) {
        a[kt][0] = *(const i32x4*)(ga0 + kt * 64);
        a[kt][1] = *(const i32x4*)(ga1 + kt * 64);
    }

    i32x4 acc[2][4] = {};
    #pragma unroll
    for (int kt = 0; kt < 8; ++kt) {
        i32x4 b0 = *(const i32x4*)(gb0 + kt * 64);
        i32x4 b1 = *(const i32x4*)(gb1 + kt * 64);
        i32x4 b2 = *(const i32x4*)(gb2 + kt * 64);
        i32x4 b3 = *(const i32x4*)(gb3 + kt * 64);
        #pragma unroll
        for (int i = 0; i < 2; ++i) {
            acc[i][0] = __builtin_amdgcn_mfma_i32_16x16x64_i8(a[kt][i], b0, acc[i][0], 0, 0, 0);
            acc[i][1] = __builtin_amdgcn_mfma_i32_16x16x64_i8(a[kt][i], b1, acc[i][1], 0, 0, 0);
            acc[i][2] = __builtin_amdgcn_mfma_i32_16x16x64_i8(a[kt][i], b2, acc[i][2], 0, 0, 0);
            acc[i][3] = __builtin_amdgcn_mfma_i32_16x16x64_i8(a[kt][i], b3, acc[i][3], 0, 0, 0);
        }
    }

    // ---- fused epilogue (int scores) ----
    // C/D layout: col = lane&15 (=lr), row = (lane>>4)*4 + reg (=kc*4+r)
    #pragma unroll
    for (int i = 0; i < 2; ++i) {
        #pragma unroll
        for (int r = 0; r < 4; ++r) {
            int v = acc[i][0][r];
            int c = j0 + lr;
            #pragma unroll
            for (int j = 1; j < 4; ++j) {
                int vj = acc[i][j][r];
                int cj = j0 + j * 16 + lr;
                if (vj > v) { v = vj; c = cj; }
            }
            #pragma unroll
            for (int off = 1; off < 16; off <<= 1) {
                int ov = __shfl_xor(v, off, 64);
                int oc = __shfl_xor(c, off, 64);
                if (ov > v || (ov == v && oc < c)) { v = ov; c = oc; }
            }
            if (lr == 0) {
                int grow = wr0 + i * 16 + kc * 4 + r;
                u64 pk = ((u64)(u32)(v ^ 0x80000000) << 32) | (u64)(~(u32)c);
                atomicMax(rowpack + grow, pk);
            }
        }
    }
    #pragma unroll
    for (int j = 0; j < 4; ++j) {
        int m = acc[0][j][0];
        #pragma unroll
        for (int i = 0; i < 2; ++i)
            #pragma unroll
            for (int r = 0; r < 4; ++r) m = max(m, acc[i][j][r]);
        m = max(m, __shfl_xor(m, 16, 64));
        m = max(m, __shfl_xor(m, 32, 64));
        if (kc == 0) atomicMax(colmax + j0 + j * 16 + lr,
                               (u32)m ^ 0x80000000u);   // biased: memset(0) == -inf
    }
}

// ---------- kernel 3a: histogram of argmax slots ----------
__global__ __launch_bounds__(256) void k_hist(const u64* __restrict__ rowpack,
                                              u32* __restrict__ cnt) {
    int n = blockIdx.x * 256 + threadIdx.x;
    u64 p = rowpack[n];
    int g = (int)(~(u32)(p & 0xFFFFFFFFull));
    atomicAdd(cnt + g, 1u);
}

// ---------- kernel 3b: exclusive scan over 2048 counts (1 block, shfl) ----------
__global__ __launch_bounds__(256) void k_scan(const u32* __restrict__ cnt,
                                              u32* __restrict__ start,
                                              u32* __restrict__ cursor) {
    __shared__ u32 wsum[4];
    int t = threadIdx.x;
    int lane = t & 63, w = t >> 6;
    u32 local[8], s = 0;
    #pragma unroll
    for (int i = 0; i < 8; ++i) { local[i] = cnt[t * 8 + i]; s += local[i]; }
    u32 x = s;
    #pragma unroll
    for (int off = 1; off < 64; off <<= 1) {
        u32 y = __shfl_up(x, off, 64);
        if (lane >= off) x += y;
    }
    if (lane == 63) wsum[w] = x;
    __syncthreads();
    u32 base = 0;
    #pragma unroll
    for (int i = 0; i < 4; ++i) if (i < w) base += wsum[i];
    u32 run = base + x - s;
    #pragma unroll
    for (int i = 0; i < 8; ++i) {
        start[t * 8 + i] = run;
        cursor[t * 8 + i] = run;
        run += local[i];
    }
}

// ---------- kernel 3c: fill perm + weights ----------
__global__ __launch_bounds__(256) void k_fill(const u64* __restrict__ rowpack,
                                              const u32* __restrict__ colmax,
                                              u32* __restrict__ cursor,
                                              u32* __restrict__ perm,
                                              float* __restrict__ wval) {
    int n = blockIdx.x * 256 + threadIdx.x;
    u64 p = rowpack[n];
    int vi = (int)(((u32)(p >> 32)) ^ 0x80000000u);
    int g = (int)(~(u32)(p & 0xFFFFFFFFull));
    int cm = (int)(colmax[g] ^ 0x80000000u);
    float w = expf((float)(vi - cm) * INV_S);   // <= 1
    u32 pos = atomicAdd(cursor + g, 1u);
    perm[pos] = (u32)n;
    wval[pos] = w;
}

// ---------- kernel 4: gather + final normalize (fused) ----------
__global__ __launch_bounds__(128) void k_gather_final(const char* __restrict__ qi8,
                                                      const u32* __restrict__ start,
                                                      const u32* __restrict__ cnt,
                                                      const u32* __restrict__ perm,
                                                      const float* __restrict__ wval,
                                                      const float* __restrict__ keys,
                                                      float* __restrict__ out) {
    __shared__ float sred[2];
    int j = blockIdx.x;
    int t = threadIdx.x;
    u32 s = start[j];
    u32 e = s + cnt[j];
    float ax = 0.f, ay = 0.f, az = 0.f, aw = 0.f;
    for (u32 i = s; i < e; ++i) {
        u32 n = perm[i];
        float wq = wval[i] * (1.0f / 127.0f);   // dequantized weight
        char4 q4 = ((const char4*)(qi8 + (size_t)n * DDIM))[t];
        ax = fmaf(wq, (float)q4.x, ax);
        ay = fmaf(wq, (float)q4.y, ay);
        az = fmaf(wq, (float)q4.z, az);
        aw = fmaf(wq, (float)q4.w, aw);
    }
    float4 k4 = ((const float4*)(keys + (size_t)j * DDIM))[t];
    float4 v;
    v.x = fmaf(TEMPU, ax, k4.x);
    v.y = fmaf(TEMPU, ay, k4.y);
    v.z = fmaf(TEMPU, az, k4.z);
    v.w = fmaf(TEMPU, aw, k4.w);
    float ss = v.x * v.x + v.y * v.y + v.z * v.z + v.w * v.w;
    ss = block_reduce_sum_128(ss, sred, t);
    float inv = 1.0f / fmaxf(sqrtf(ss), EPSN);
    v.x *= inv; v.y *= inv; v.z *= inv; v.w *= inv;
    ((float4*)(out + (size_t)j * DDIM))[t] = v;
}

// ---------- launch ----------
extern "C" void kernel_launch(void* const* d_in, const int* in_sizes, int n_in,
                              void* d_out, int out_size, void* d_ws, size_t ws_size,
                              hipStream_t stream) {
    const float* query = (const float*)d_in[0];   // [16384, 512] f32
    const float* keys  = (const float*)d_in[1];   // [2048, 512] f32
    float* out = (float*)d_out;                   // [2048, 512] f32

    char* ws = (char*)d_ws;
    const size_t OFF_QI8   = 0;                        //  8,388,608 B  qi8
    const size_t OFF_ROW   = 8388608;                  //    131,072 B  rowpack u64[16384]
    const size_t OFF_CMAX  = OFF_ROW + 131072;         //      8,192 B  colmax u32 biased
    const size_t OFF_CNT   = OFF_CMAX + 8192;          //      8,192 B  cnt
    const size_t OFF_START = OFF_CNT + 8192;           //      8,192 B
    const size_t OFF_CUR   = OFF_START + 8192;         //      8,192 B
    const size_t OFF_PERM  = OFF_CUR + 8192;           //     65,536 B
    const size_t OFF_W     = OFF_PERM + 65536;         //     65,536 B
    const size_t OFF_KI8   = OFF_W + 65536;            //  1,048,576 B

    char*   qi8    = ws + OFF_QI8;
    u64*    rowpack= (u64*)(ws + OFF_ROW);
    u32*    cmax   = (u32*)(ws + OFF_CMAX);
    u32*    cnt    = (u32*)(ws + OFF_CNT);
    u32*    start  = (u32*)(ws + OFF_START);
    u32*    cursor = (u32*)(ws + OFF_CUR);
    u32*    perm   = (u32*)(ws + OFF_PERM);
    float*  wval   = (float*)(ws + OFF_W);
    char*   ki8    = ws + OFF_KI8;

    // one memset: rowpack (packed vals > 0) + biased colmax + cnt -> 0
    hipMemsetAsync(ws + OFF_ROW, 0, 131072 + 8192 + 8192, stream);

    k_prep<<<N_Q + M_SLOTS, 128, 0, stream>>>(query, keys, qi8, ki8);

    dim3 g2(M_SLOTS / 64, N_Q / 128);  // 32 x 128
    k_score<<<g2, 256, 0, stream>>>(qi8, ki8, rowpack, cmax);

    k_hist<<<N_Q / 256, 256, 0, stream>>>(rowpack, cnt);
    k_scan<<<1, 256, 0, stream>>>(cnt, start, cursor);
    k_fill<<<N_Q / 256, 256, 0, stream>>>(rowpack, cmax, cursor, perm, wval);
    k_gather_final<<<M_SLOTS, 128, 0, stream>>>(qi8, start, cnt, perm, wval, keys, out);
}

// Round 10
// 83.721 us; speedup vs baseline: 1.5278x; 1.5278x over previous
//
#include <hip/hip_runtime.h>
#include <math.h>

#define N_Q     16384
#define DDIM    512
#define M_SLOTS 2048
#define EPSN    1e-12f
#define TEMPU   1e-5f
#define KSCALE  25.4f                    // int8 scale for keys (clips at ~5 sigma)
#define QSCALE  127.0f
#define INV_S   (1.0f / (127.0f * 25.4f))

typedef unsigned int u32;
typedef unsigned long long u64;
typedef __attribute__((ext_vector_type(4))) int i32x4;

// ---------- helpers ----------
__device__ __forceinline__ void gld_lds16(const void* g, void* l) {
    __builtin_amdgcn_global_load_lds(
        (const __attribute__((address_space(1))) u32*)(g),
        (__attribute__((address_space(3))) u32*)(l), 16, 0, 0);
}
__device__ __forceinline__ float block_reduce_sum_128(float v, float* sred, int t) {
    #pragma unroll
    for (int o = 32; o > 0; o >>= 1) v += __shfl_down(v, o, 64);
    if ((t & 63) == 0) sred[t >> 6] = v;
    __syncthreads();
    return sred[0] + sred[1];
}
__device__ __forceinline__ char q8(float x, float s) {
    int v = __float2int_rn(x * s);
    v = v < -127 ? -127 : (v > 127 ? 127 : v);
    return (char)v;
}

// ---------- kernel 1: normalize+quantize queries (blocks 0..N_Q-1), keys->i8 (last 2048) ----------
__global__ __launch_bounds__(128) void k_prep(const float* __restrict__ q,
                                              const float* __restrict__ keys,
                                              char* __restrict__ qi8,
                                              char* __restrict__ ki8) {
    __shared__ float sred[2];
    int b = blockIdx.x;
    int t = threadIdx.x;
    if (b < N_Q) {
        float4 v = ((const float4*)(q + (size_t)b * DDIM))[t];
        float ss = v.x * v.x + v.y * v.y + v.z * v.z + v.w * v.w;
        ss = block_reduce_sum_128(ss, sred, t);
        float s = QSCALE / fmaxf(sqrtf(ss), EPSN);
        char4 o;
        o.x = q8(v.x, s);
        o.y = q8(v.y, s);
        o.z = q8(v.z, s);
        o.w = q8(v.w, s);
        ((char4*)(qi8 + (size_t)b * DDIM))[t] = o;
    } else {
        int r = b - N_Q;
        float4 v = ((const float4*)(keys + (size_t)r * DDIM))[t];
        char4 o;
        o.x = q8(v.x, KSCALE);
        o.y = q8(v.y, KSCALE);
        o.z = q8(v.z, KSCALE);
        o.w = q8(v.w, KSCALE);
        ((char4*)(ki8 + (size_t)r * DDIM))[t] = o;
    }
}

// ---------- kernel 2: i8 MFMA score GEMM, 256x256 tile, depth-2 counted vmcnt ----------
// 512 threads / 8 waves (2 wrow x 4 wcol), wave subtile 128x64 (8x4 frags).
// BK=64 i8, 8 K-steps, 3 LDS buffers (96 KB), stage kt+2 while computing kt,
// s_waitcnt vmcnt(4) + raw s_barrier per step. MFMA:staging ratio 2x round-7.
__global__ __launch_bounds__(512, 2) void k_score(const char* __restrict__ qi8,
                                                  const char* __restrict__ ki8,
                                                  u64* __restrict__ rowpack,
                                                  u32* __restrict__ colmax) {
    __shared__ char sA[3][256 * 64];   // 48 KB
    __shared__ char sB[3][256 * 64];   // 48 KB

    int t = threadIdx.x;
    int lane = t & 63;
    int wid = t >> 6;            // 0..7
    int wrow = wid >> 2;         // 0..1 -> 128-row half
    int wcol = wid & 3;          // 0..3 -> 64-col quarter
    int lr = lane & 15;          // frag row (A) / col (B)
    int kc = lane >> 4;          // k-chunk 0..3 (16 i8 each)

    int j0 = blockIdx.x * 256;   // slot block
    int n0 = blockIdx.y * 256;   // query block

    int srow = t >> 2;           // 0..127
    int scolB = (t & 3) * 16;    // byte offset within 64B row

    const char* gA0 = qi8 + (size_t)(n0 + srow) * DDIM + scolB;
    const char* gA1 = qi8 + (size_t)(n0 + 128 + srow) * DDIM + scolB;
    const char* gB0 = ki8 + (size_t)(j0 + srow) * DDIM + scolB;
    const char* gB1 = ki8 + (size_t)(j0 + 128 + srow) * DDIM + scolB;

    i32x4 acc[8][4] = {};

#define STAGE(buf, k0)  do {                                   \
        gld_lds16(gA0 + (k0), &sA[buf][t * 16]);               \
        gld_lds16(gA1 + (k0), &sA[buf][8192 + t * 16]);        \
        gld_lds16(gB0 + (k0), &sB[buf][t * 16]);               \
        gld_lds16(gB1 + (k0), &sB[buf][8192 + t * 16]);        \
    } while (0)

    // prologue: 2 stages in flight; wait for the oldest (4 newest may remain)
    STAGE(0, 0);
    STAGE(1, 64);
    asm volatile("s_waitcnt vmcnt(4)" ::: "memory");
    __builtin_amdgcn_s_barrier();
    __builtin_amdgcn_sched_barrier(0);

    #pragma unroll
    for (int kt = 0; kt < 8; ++kt) {
        const int cur = kt % 3;
        if (kt < 6) STAGE((kt + 2) % 3, (kt + 2) * 64);

        i32x4 a[8], b[4];
        #pragma unroll
        for (int i = 0; i < 8; ++i)
            a[i] = *(const i32x4*)&sA[cur][(wrow * 128 + i * 16 + lr) * 64 + kc * 16];
        #pragma unroll
        for (int j = 0; j < 4; ++j)
            b[j] = *(const i32x4*)&sB[cur][(wcol * 64 + j * 16 + lr) * 64 + kc * 16];
        #pragma unroll
        for (int i = 0; i < 8; ++i)
            #pragma unroll
            for (int j = 0; j < 4; ++j)
                acc[i][j] = __builtin_amdgcn_mfma_i32_16x16x64_i8(a[i], b[j], acc[i][j], 0, 0, 0);

        // gate NEXT buffer: wait for stage kt+1; keep this iter's stage in flight
        if (kt < 6)       asm volatile("s_waitcnt vmcnt(4)" ::: "memory");
        else if (kt == 6) asm volatile("s_waitcnt vmcnt(0)" ::: "memory");
        if (kt < 7) {
            __builtin_amdgcn_s_barrier();
            __builtin_amdgcn_sched_barrier(0);
        }
    }
#undef STAGE

    // ---- fused epilogue (int scores) ----
    // C/D layout: col = lane&15 (=lr), row = (lane>>4)*4 + reg (=kc*4+r)
    #pragma unroll
    for (int i = 0; i < 8; ++i) {
        #pragma unroll
        for (int r = 0; r < 4; ++r) {
            int v = acc[i][0][r];
            int c = j0 + wcol * 64 + lr;
            #pragma unroll
            for (int j = 1; j < 4; ++j) {
                int vj = acc[i][j][r];
                int cj = j0 + wcol * 64 + j * 16 + lr;
                if (vj > v) { v = vj; c = cj; }
            }
            #pragma unroll
            for (int off = 1; off < 16; off <<= 1) {
                int ov = __shfl_xor(v, off, 64);
                int oc = __shfl_xor(c, off, 64);
                if (ov > v || (ov == v && oc < c)) { v = ov; c = oc; }
            }
            if (lr == 0) {
                int grow = n0 + wrow * 128 + i * 16 + kc * 4 + r;
                u64 pk = ((u64)(u32)(v ^ 0x80000000) << 32) | (u64)(~(u32)c);
                atomicMax(rowpack + grow, pk);
            }
        }
    }
    #pragma unroll
    for (int j = 0; j < 4; ++j) {
        int m = acc[0][j][0];
        #pragma unroll
        for (int i = 0; i < 8; ++i)
            #pragma unroll
            for (int r = 0; r < 4; ++r) m = max(m, acc[i][j][r]);
        m = max(m, __shfl_xor(m, 16, 64));
        m = max(m, __shfl_xor(m, 32, 64));
        if (kc == 0) atomicMax(colmax + j0 + wcol * 64 + j * 16 + lr,
                               (u32)m ^ 0x80000000u);   // biased: memset(0) == -inf
    }
}

// ---------- kernel 3a: histogram of argmax slots ----------
__global__ __launch_bounds__(256) void k_hist(const u64* __restrict__ rowpack,
                                              u32* __restrict__ cnt) {
    int n = blockIdx.x * 256 + threadIdx.x;
    u64 p = rowpack[n];
    int g = (int)(~(u32)(p & 0xFFFFFFFFull));
    atomicAdd(cnt + g, 1u);
}

// ---------- kernel 3b: exclusive scan over 2048 counts (1 block, shfl) ----------
__global__ __launch_bounds__(256) void k_scan(const u32* __restrict__ cnt,
                                              u32* __restrict__ start,
                                              u32* __restrict__ cursor) {
    __shared__ u32 wsum[4];
    int t = threadIdx.x;
    int lane = t & 63, w = t >> 6;
    u32 local[8], s = 0;
    #pragma unroll
    for (int i = 0; i < 8; ++i) { local[i] = cnt[t * 8 + i]; s += local[i]; }
    u32 x = s;
    #pragma unroll
    for (int off = 1; off < 64; off <<= 1) {
        u32 y = __shfl_up(x, off, 64);
        if (lane >= off) x += y;
    }
    if (lane == 63) wsum[w] = x;
    __syncthreads();
    u32 base = 0;
    #pragma unroll
    for (int i = 0; i < 4; ++i) if (i < w) base += wsum[i];
    u32 run = base + x - s;
    #pragma unroll
    for (int i = 0; i < 8; ++i) {
        start[t * 8 + i] = run;
        cursor[t * 8 + i] = run;
        run += local[i];
    }
}

// ---------- kernel 3c: fill perm + weights ----------
__global__ __launch_bounds__(256) void k_fill(const u64* __restrict__ rowpack,
                                              const u32* __restrict__ colmax,
                                              u32* __restrict__ cursor,
                                              u32* __restrict__ perm,
                                              float* __restrict__ wval) {
    int n = blockIdx.x * 256 + threadIdx.x;
    u64 p = rowpack[n];
    int vi = (int)(((u32)(p >> 32)) ^ 0x80000000u);
    int g = (int)(~(u32)(p & 0xFFFFFFFFull));
    int cm = (int)(colmax[g] ^ 0x80000000u);
    float w = expf((float)(vi - cm) * INV_S);   // <= 1
    u32 pos = atomicAdd(cursor + g, 1u);
    perm[pos] = (u32)n;
    wval[pos] = w;
}

// ---------- kernel 4: gather + final normalize (fused) ----------
__global__ __launch_bounds__(128) void k_gather_final(const char* __restrict__ qi8,
                                                      const u32* __restrict__ start,
                                                      const u32* __restrict__ cnt,
                                                      const u32* __restrict__ perm,
                                                      const float* __restrict__ wval,
                                                      const float* __restrict__ keys,
                                                      float* __restrict__ out) {
    __shared__ float sred[2];
    int j = blockIdx.x;
    int t = threadIdx.x;
    u32 s = start[j];
    u32 e = s + cnt[j];
    float ax = 0.f, ay = 0.f, az = 0.f, aw = 0.f;
    for (u32 i = s; i < e; ++i) {
        u32 n = perm[i];
        float wq = wval[i] * (1.0f / 127.0f);   // dequantized weight
        char4 q4 = ((const char4*)(qi8 + (size_t)n * DDIM))[t];
        ax = fmaf(wq, (float)q4.x, ax);
        ay = fmaf(wq, (float)q4.y, ay);
        az = fmaf(wq, (float)q4.z, az);
        aw = fmaf(wq, (float)q4.w, aw);
    }
    float4 k4 = ((const float4*)(keys + (size_t)j * DDIM))[t];
    float4 v;
    v.x = fmaf(TEMPU, ax, k4.x);
    v.y = fmaf(TEMPU, ay, k4.y);
    v.z = fmaf(TEMPU, az, k4.z);
    v.w = fmaf(TEMPU, aw, k4.w);
    float ss = v.x * v.x + v.y * v.y + v.z * v.z + v.w * v.w;
    ss = block_reduce_sum_128(ss, sred, t);
    float inv = 1.0f / fmaxf(sqrtf(ss), EPSN);
    v.x *= inv; v.y *= inv; v.z *= inv; v.w *= inv;
    ((float4*)(out + (size_t)j * DDIM))[t] = v;
}

// ---------- launch ----------
extern "C" void kernel_launch(void* const* d_in, const int* in_sizes, int n_in,
                              void* d_out, int out_size, void* d_ws, size_t ws_size,
                              hipStream_t stream) {
    const float* query = (const float*)d_in[0];   // [16384, 512] f32
    const float* keys  = (const float*)d_in[1];   // [2048, 512] f32
    float* out = (float*)d_out;                   // [2048, 512] f32

    char* ws = (char*)d_ws;
    const size_t OFF_QI8   = 0;                        //  8,388,608 B  qi8
    const size_t OFF_ROW   = 8388608;                  //    131,072 B  rowpack u64[16384]
    const size_t OFF_CMAX  = OFF_ROW + 131072;         //      8,192 B  colmax u32 biased
    const size_t OFF_CNT   = OFF_CMAX + 8192;          //      8,192 B  cnt
    const size_t OFF_START = OFF_CNT + 8192;           //      8,192 B
    const size_t OFF_CUR   = OFF_START + 8192;         //      8,192 B
    const size_t OFF_PERM  = OFF_CUR + 8192;           //     65,536 B
    const size_t OFF_W     = OFF_PERM + 65536;         //     65,536 B
    const size_t OFF_KI8   = OFF_W + 65536;            //  1,048,576 B

    char*   qi8    = ws + OFF_QI8;
    u64*    rowpack= (u64*)(ws + OFF_ROW);
    u32*    cmax   = (u32*)(ws + OFF_CMAX);
    u32*    cnt    = (u32*)(ws + OFF_CNT);
    u32*    start  = (u32*)(ws + OFF_START);
    u32*    cursor = (u32*)(ws + OFF_CUR);
    u32*    perm   = (u32*)(ws + OFF_PERM);
    float*  wval   = (float*)(ws + OFF_W);
    char*   ki8    = ws + OFF_KI8;

    // one memset: rowpack (packed vals > 0) + biased colmax + cnt -> 0
    hipMemsetAsync(ws + OFF_ROW, 0, 131072 + 8192 + 8192, stream);

    k_prep<<<N_Q + M_SLOTS, 128, 0, stream>>>(query, keys, qi8, ki8);

    dim3 g2(M_SLOTS / 256, N_Q / 256);  // 8 x 64
    k_score<<<g2, 512, 0, stream>>>(qi8, ki8, rowpack, cmax);

    k_hist<<<N_Q / 256, 256, 0, stream>>>(rowpack, cnt);
    k_scan<<<1, 256, 0, stream>>>(cnt, start, cursor);
    k_fill<<<N_Q / 256, 256, 0, stream>>>(rowpack, cmax, cursor, perm, wval);
    k_gather_final<<<M_SLOTS, 128, 0, stream>>>(qi8, start, cnt, perm, wval, keys, out);
}